// Round 7
// baseline (184.615 us; speedup 1.0000x reference)
//
#include <hip/hip_runtime.h>
#include <hip/hip_bf16.h>

// CILRS head, MI355X round 7.
// Theory: rounds 2/5/6 all ~150us because each barrier-section stages ~24KB
// through LDS (global_load_lds fill throughput ~7-16 B/cyc/CU is the shared
// bottleneck; matches m97/m233). Fix: B-fragments are per-wave-private ->
// load B global->registers directly (no LDS, no DMA, no conflicts). Only A
// (cross-wave shared) stays in LDS: 8KB/section, gll dbuf, counted vmcnt.
// Layer 2 has NO barriers (Y read-only, B in regs). LDS 48KB -> 3 blocks/CU.
// B-loads issued BEFORE A-glls so compiler's pre-MFMA wait is vmcnt(2).
// ws layout (bytes):
//   0        spb      : B*128 bf16 sp-latent (16,777,216)
//   16777216 perm     : (B+384) int32                 -> 17,040,896
//   17040896 bcnt     : [1024][6] int                 -> 17,065,472
//   17065472 chunkoff : [1024][6] int                 -> 17,090,048
//   17090048 pad      : pad[0..6]=offsets, pad[8+g]=totals (64 ints)
//   17090304 Wsi2T    : [128][256] bf16
//   17155840 Wso1T    : [256][640] bf16
//   17483520 Wso2T    : [256][256] bf16
//   17614592 Wb1T     : [6][256][640] bf16
//   19580672 Wb2T     : [6][256][256] bf16  (end 20,367,104)

#define NB 65536
#define NBRB 1030   // branch-region blocks; speed region follows

typedef __attribute__((ext_vector_type(8))) short short8;
typedef __attribute__((ext_vector_type(4))) float f32x4;
typedef unsigned short bhalf;
typedef unsigned int u32;

__device__ __forceinline__ bhalf f2b(float x) {
    __hip_bfloat16 h = __float2bfloat16(x);
    return *reinterpret_cast<bhalf*>(&h);
}
__device__ __forceinline__ void gll16(const void* g, void* l) {
    __builtin_amdgcn_global_load_lds(
        (const __attribute__((address_space(1))) u32*)g,
        (__attribute__((address_space(3))) u32*)l, 16, 0, 0);
}
// 64B-row bf16 tile (sp-A): phys = row*64 + (cb ^ (((row>>1)&3)<<4))
__device__ __forceinline__ int sadr(int row, int cb) {
    return row * 64 + (cb ^ (((row >> 1) & 3) << 4));
}
// 512B-row tile (Y): phys = row*512 + (cb ^ ((row&7)<<4))
__device__ __forceinline__ int yadr(int row, int cb) {
    return row * 512 + (cb ^ ((row & 7) << 4));
}
__device__ __forceinline__ void wvm6() { asm volatile("s_waitcnt vmcnt(6)" ::: "memory"); }
__device__ __forceinline__ void wvm4() { asm volatile("s_waitcnt vmcnt(4)" ::: "memory"); }
__device__ __forceinline__ void wlgkm0() { asm volatile("s_waitcnt lgkmcnt(0)" ::: "memory"); }

// -------- weight transpose, 64x64 LDS tiles --------
__global__ __launch_bounds__(256) void k_wprep(
    const float* __restrict__ Wsi2, const float* __restrict__ Wso1,
    const float* __restrict__ Wso2, const float* __restrict__ Wb1,
    const float* __restrict__ Wb2,
    bhalf* __restrict__ Wsi2T, bhalf* __restrict__ Wso1T,
    bhalf* __restrict__ Wso2T, bhalf* __restrict__ Wb1T,
    bhalf* __restrict__ Wb2T) {
    __shared__ float T[64][65];
    const int id = blockIdx.x, t = threadIdx.x;
    const float* src; bhalf* dst; int K, N, tk, tn, b;
    if (id < 8)        { src = Wsi2; dst = Wsi2T; K = 256; N = 128; b = 0; int tl = id;      tk = tl / 2; tn = tl % 2; }
    else if (id < 48)  { src = Wso1; dst = Wso1T; K = 640; N = 256; b = 0; int tl = id - 8;  tk = tl / 4; tn = tl % 4; }
    else if (id < 64)  { src = Wso2; dst = Wso2T; K = 256; N = 256; b = 0; int tl = id - 48; tk = tl / 4; tn = tl % 4; }
    else if (id < 304) { src = Wb1;  dst = Wb1T;  K = 640; N = 256; int li = id - 64;  b = li / 40; int tl = li % 40; tk = tl / 4; tn = tl % 4; }
    else               { src = Wb2;  dst = Wb2T;  K = 256; N = 256; int li = id - 304; b = li / 16; int tl = li % 16; tk = tl / 4; tn = tl % 4; }
    const int k0 = tk * 64, n0 = tn * 64;
    src += (size_t)b * K * N; dst += (size_t)b * N * K;
    const int c = t & 63, r0 = t >> 6;
#pragma unroll
    for (int j = 0; j < 16; ++j) {
        int r = r0 + j * 4;
        T[r][c] = src[(size_t)(k0 + r) * N + n0 + c];
    }
    __syncthreads();
#pragma unroll
    for (int j = 0; j < 16; ++j) {
        int r = r0 + j * 4;
        dst[(size_t)(n0 + r) * K + k0 + c] = f2b(T[c][r]);
    }
}

// speed-latent + per-chunk command counts (NO atomics)
__global__ __launch_bounds__(256) void k_prep(
    const float* __restrict__ speed, const float* __restrict__ Wsi1,
    const float* __restrict__ bsi1, const bhalf* __restrict__ Wsi2T,
    const float* __restrict__ bsi2, const int* __restrict__ cmd,
    bhalf* __restrict__ spb, int* __restrict__ bcnt) {
    __shared__ bhalf A[64 * 72];
    __shared__ bhalf BT[128 * 72];
    const int t = threadIdx.x, lane = t & 63, wid = t >> 6;
    const int rbase = blockIdx.x * 64;
    if (wid == 0) {                      // chunk histogram by wave 0
        int c = cmd[rbase + lane] - 1;
        int v = 0;
#pragma unroll
        for (int g = 0; g < 6; ++g) {
            unsigned long long m = __ballot(c == g);
            if (lane == g) v = (int)__popcll(m);
        }
        if (lane < 6) bcnt[blockIdx.x * 6 + lane] = v;
    }
    const int wm = wid >> 1, wn = wid & 1;
    f32x4 acc[2][4];
    for (int m = 0; m < 2; ++m) for (int n = 0; n < 4; ++n)
        for (int r = 0; r < 4; ++r) acc[m][n][r] = 0.f;
    const int ar = t >> 2, kp = (t & 3) * 16;
    const float s = speed[rbase + ar];
    for (int kc = 0; kc < 4; ++kc) {
        short8 w0, w1;
#pragma unroll
        for (int j = 0; j < 8; ++j) {
            int k = kc * 64 + kp + j;
            w0[j] = (short)f2b(fmaxf(fmaf(s, Wsi1[k], bsi1[k]), 0.f));
            w1[j] = (short)f2b(fmaxf(fmaf(s, Wsi1[k + 8], bsi1[k + 8]), 0.f));
        }
        *(short8*)&A[ar * 72 + kp] = w0;
        *(short8*)&A[ar * 72 + kp + 8] = w1;
#pragma unroll
        for (int j = 0; j < 4; ++j) {
            int ch = t + j * 256;
            int n2 = ch >> 3, ko = (ch & 7) * 8;
            *(short8*)&BT[n2 * 72 + ko] =
                *(const short8*)(Wsi2T + n2 * 256 + kc * 64 + ko);
        }
        __syncthreads();
#pragma unroll
        for (int ks = 0; ks < 2; ++ks) {
            short8 a[2], b[4];
#pragma unroll
            for (int m = 0; m < 2; ++m)
                a[m] = *(const short8*)&A[(wm * 32 + m * 16 + (lane & 15)) * 72 + ks * 32 + (lane >> 4) * 8];
#pragma unroll
            for (int n = 0; n < 4; ++n)
                b[n] = *(const short8*)&BT[(wn * 64 + n * 16 + (lane & 15)) * 72 + ks * 32 + (lane >> 4) * 8];
#pragma unroll
            for (int m = 0; m < 2; ++m)
#pragma unroll
                for (int n = 0; n < 4; ++n)
                    acc[m][n] = __builtin_amdgcn_mfma_f32_16x16x32_bf16(a[m], b[n], acc[m][n], 0, 0, 0);
        }
        __syncthreads();
    }
#pragma unroll
    for (int m = 0; m < 2; ++m)
#pragma unroll
    for (int n = 0; n < 4; ++n) {
        int col = wn * 64 + n * 16 + (lane & 15);
        float bias = bsi2[col];
#pragma unroll
        for (int r = 0; r < 4; ++r) {
            int row = rbase + wm * 32 + m * 16 + (lane >> 4) * 4 + r;
            spb[row * 128 + col] = f2b(acc[m][n][r] + bias);
        }
    }
}

// 1 block, 1024 threads: prefix-scan chunk counts -> chunk bases + pad table
__global__ __launch_bounds__(1024) void k_scan(
    const int* __restrict__ bcnt, int* __restrict__ chunkoff,
    int* __restrict__ pad) {
    __shared__ int sc[1024];
    __shared__ int tot[8];
    __shared__ int spo[8];
    const int t = threadIdx.x;
    for (int g = 0; g < 6; ++g) {
        int v = bcnt[t * 6 + g];
        sc[t] = v;
        __syncthreads();
        for (int s = 1; s < 1024; s <<= 1) {
            int u = (t >= s) ? sc[t - s] : 0;
            __syncthreads();
            sc[t] += u;
            __syncthreads();
        }
        if (t == 1023) tot[g] = sc[t];
        chunkoff[t * 6 + g] = sc[t] - v;
        __syncthreads();
    }
    if (t == 0) {
        int off = 0;
        for (int g = 0; g < 6; ++g) {
            spo[g] = off; pad[g] = off; pad[8 + g] = tot[g];
            off += ((tot[g] + 63) >> 6) << 6;
        }
        spo[6] = off; pad[6] = off;
    }
    __syncthreads();
    for (int g = 0; g < 6; ++g) chunkoff[t * 6 + g] += spo[g];
}

// deterministic scatter, no atomics
__global__ __launch_bounds__(256) void k_scatter(
    const int* __restrict__ cmd, const int* __restrict__ chunkoff,
    int* __restrict__ perm) {
    const int lane = threadIdx.x & 63, w = threadIdx.x >> 6;
    const int chunk = blockIdx.x * 4 + w;
    const int idx = chunk * 64 + lane;
    const int c = cmd[idx] - 1;
#pragma unroll
    for (int g = 0; g < 6; ++g) {
        unsigned long long m = __ballot(c == g);
        if (c == g) {
            int pos = chunkoff[chunk * 6 + g] + (int)__popcll(m & ((1ull << lane) - 1ull));
            perm[pos] = idx;
        }
    }
}

// -------- fused 3-layer head: A via gll-dbuf LDS, B direct global->reg ------
__global__ __launch_bounds__(256, 3) void k_head(
    const float* __restrict__ emb, const bhalf* __restrict__ spb,
    const bhalf* __restrict__ Wso1T, const float* __restrict__ bso1,
    const bhalf* __restrict__ Wso2T, const float* __restrict__ bso2,
    const float* __restrict__ Wso3, const float* __restrict__ bso3,
    const bhalf* __restrict__ Wb1T, const float* __restrict__ bb1,
    const bhalf* __restrict__ Wb2T, const float* __restrict__ bb2,
    const float* __restrict__ Wb3, const float* __restrict__ bb3,
    const int* __restrict__ pad, const int* __restrict__ perm,
    float* __restrict__ out) {
    __shared__ __align__(16) char SA[2][8192];   // A dbuf: f32 [64][32k] (sp bf16 in low 4K)
    __shared__ __align__(16) char Yb[32768];     // Y bf16 [64][256] swz
    const int t = threadIdx.x, lane = t & 63, wid = t >> 6;
    const bool isB = blockIdx.x < NBRB;
    int tstart, DOUT, gcnt, gbase;
    const bhalf *W1T, *W2T; const float *b1, *b2, *W3, *b3;
    if (isB) {
        tstart = blockIdx.x * 64;
        if (tstart >= pad[6]) return;
        int g = 0;
        while (pad[g + 1] <= tstart) ++g;
        gbase = pad[g]; gcnt = pad[8 + g];
        W1T = Wb1T + (size_t)g * (256 * 640); b1 = bb1 + g * 256;
        W2T = Wb2T + (size_t)g * (256 * 256); b2 = bb2 + g * 256;
        W3  = Wb3  + (size_t)g * (256 * 3);   b3 = bb3 + g * 3;
        DOUT = 3;
    } else {
        tstart = (blockIdx.x - NBRB) * 64;
        gbase = 0; gcnt = NB;
        W1T = Wso1T; b1 = bso1; W2T = Wso2T; b2 = bso2; W3 = Wso3; b3 = bso3;
        DOUT = 1;
    }

    // A staging source maps (gll: linear dest, inverse-swizzled source)
    const int rowA0 = t >> 3, rowA1 = rowA0 + 32, rowS = t >> 2;
    int ra0, ra1, raS;
    if (isB) {
        int p0 = tstart + rowA0, p1 = tstart + rowA1, pS = tstart + rowS;
        ra0 = ((p0 - gbase) < gcnt) ? perm[p0] : 0;
        ra1 = ((p1 - gbase) < gcnt) ? perm[p1] : 0;
        raS = ((pS - gbase) < gcnt) ? perm[pS] : 0;
    } else {
        ra0 = tstart + rowA0; ra1 = tstart + rowA1; raS = tstart + rowS;
    }
    const int lcA0 = ((t & 7) * 16) ^ ((rowA0 & 7) << 4);
    const int lcA1 = ((t & 7) * 16) ^ ((rowA1 & 7) << 4);
    const int lcS  = ((t & 3) * 16) ^ (((rowS >> 1) & 3) << 4);
    const char* embp0 = (const char*)(emb + (size_t)ra0 * 512);
    const char* embp1 = (const char*)(emb + (size_t)ra1 * 512);
    const char* spbp  = (const char*)(spb + (size_t)raS * 128);
    const int dstA = t * 16;

#define ST_A(KN, BUF) do { int kn_ = (KN); char* d_ = &SA[BUF][0] + dstA;        \
        if (kn_ < 16) {                                                           \
            gll16(embp0 + kn_ * 128 + lcA0, d_);                                  \
            gll16(embp1 + kn_ * 128 + lcA1, d_ + 4096);                           \
        } else {                                                                  \
            gll16(spbp + (kn_ - 16) * 64 + lcS, d_);                              \
            gll16(spbp + (kn_ - 16) * 64 + lcS, d_ + 4096);                       \
        } } while (0)

    const int arow = lane & 15, koff = (lane >> 4) * 16;
    // B-fragment direct-global pointers: column = wid*64 + n*16 + arow,
    // k-bytes (lane>>4)*16, row stride 1280 (W1T) / 512 (W2T).
    const int kb = (lane >> 4) * 16;
    const char* bp0 = (const char*)W1T + (size_t)(wid * 64 + 0  + arow) * 1280 + kb;
    const char* bp1 = (const char*)W1T + (size_t)(wid * 64 + 16 + arow) * 1280 + kb;
    const char* bp2 = (const char*)W1T + (size_t)(wid * 64 + 32 + arow) * 1280 + kb;
    const char* bp3 = (const char*)W1T + (size_t)(wid * 64 + 48 + arow) * 1280 + kb;

    // preload biases
    float bi1[4], bi2[4];
#pragma unroll
    for (int n = 0; n < 4; ++n) {
        bi1[n] = b1[wid * 64 + n * 16 + arow];
        bi2[n] = b2[wid * 64 + n * 16 + arow];
    }

    f32x4 acc[4][4];
#pragma unroll
    for (int m = 0; m < 4; ++m)
#pragma unroll
        for (int n = 0; n < 4; ++n)
#pragma unroll
            for (int r = 0; r < 4; ++r) acc[m][n][r] = 0.f;

    // ---------------- layer 1: K=640, 20 sections ----------------
    // Per section: [4 B-reg loads (older)] [2 A-glls for next (newer)]
    // -> wvm6 = prev A-glls done; compiler waits B with vmcnt(2).
    ST_A(0, 0);
    for (int kc = 0; kc < 20; ++kc) {
        const int buf = kc & 1;
        short8 b0 = *(const short8*)(bp0 + kc * 64);
        short8 b1f = *(const short8*)(bp1 + kc * 64);
        short8 b2f = *(const short8*)(bp2 + kc * 64);
        short8 b3f = *(const short8*)(bp3 + kc * 64);
        if (kc < 19) { ST_A(kc + 1, buf ^ 1); wvm6(); }
        else         { wvm4(); }
        __builtin_amdgcn_s_barrier();
        const char* SAc = &SA[buf][0];
        short8 a[4];
        if (kc < 16) {
#pragma unroll
            for (int m = 0; m < 4; ++m) {
                int row = m * 16 + arow;
                int sw = (row & 7) << 4;
                int c0 = (lane >> 4) * 32;
                float4 f0 = *(const float4*)(SAc + row * 128 + (c0 ^ sw));
                float4 f1 = *(const float4*)(SAc + row * 128 + ((c0 + 16) ^ sw));
                a[m][0] = (short)f2b(f0.x); a[m][1] = (short)f2b(f0.y);
                a[m][2] = (short)f2b(f0.z); a[m][3] = (short)f2b(f0.w);
                a[m][4] = (short)f2b(f1.x); a[m][5] = (short)f2b(f1.y);
                a[m][6] = (short)f2b(f1.z); a[m][7] = (short)f2b(f1.w);
            }
        } else {
#pragma unroll
            for (int m = 0; m < 4; ++m)
                a[m] = *(const short8*)(SAc + sadr(m * 16 + arow, koff));
        }
#pragma unroll
        for (int m = 0; m < 4; ++m) {
            acc[m][0] = __builtin_amdgcn_mfma_f32_16x16x32_bf16(a[m], b0,  acc[m][0], 0, 0, 0);
            acc[m][1] = __builtin_amdgcn_mfma_f32_16x16x32_bf16(a[m], b1f, acc[m][1], 0, 0, 0);
            acc[m][2] = __builtin_amdgcn_mfma_f32_16x16x32_bf16(a[m], b2f, acc[m][2], 0, 0, 0);
            acc[m][3] = __builtin_amdgcn_mfma_f32_16x16x32_bf16(a[m], b3f, acc[m][3], 0, 0, 0);
        }
        __builtin_amdgcn_s_barrier();
    }
    // epi 1: bias+relu -> Y
#pragma unroll
    for (int m = 0; m < 4; ++m)
#pragma unroll
    for (int n = 0; n < 4; ++n) {
        int col = wid * 64 + n * 16 + arow;
#pragma unroll
        for (int r = 0; r < 4; ++r) {
            int row = m * 16 + (lane >> 4) * 4 + r;
            *(bhalf*)(Yb + yadr(row, 2 * col)) = f2b(fmaxf(acc[m][n][r] + bi1[n], 0.f));
            acc[m][n][r] = 0.f;
        }
    }
    wlgkm0();
    __builtin_amdgcn_s_barrier();
    // ---------------- layer 2: K=256, 8 sections, NO barriers ---------------
    {
        const char* cp0 = (const char*)W2T + (size_t)(wid * 64 + 0  + arow) * 512 + kb;
        const char* cp1 = (const char*)W2T + (size_t)(wid * 64 + 16 + arow) * 512 + kb;
        const char* cp2 = (const char*)W2T + (size_t)(wid * 64 + 32 + arow) * 512 + kb;
        const char* cp3 = (const char*)W2T + (size_t)(wid * 64 + 48 + arow) * 512 + kb;
        for (int kc = 0; kc < 8; ++kc) {
            short8 b0 = *(const short8*)(cp0 + kc * 64);
            short8 b1f = *(const short8*)(cp1 + kc * 64);
            short8 b2f = *(const short8*)(cp2 + kc * 64);
            short8 b3f = *(const short8*)(cp3 + kc * 64);
            short8 a[4];
#pragma unroll
            for (int m = 0; m < 4; ++m)
                a[m] = *(const short8*)(Yb + yadr(m * 16 + arow, kc * 64 + koff));
#pragma unroll
            for (int m = 0; m < 4; ++m) {
                acc[m][0] = __builtin_amdgcn_mfma_f32_16x16x32_bf16(a[m], b0,  acc[m][0], 0, 0, 0);
                acc[m][1] = __builtin_amdgcn_mfma_f32_16x16x32_bf16(a[m], b1f, acc[m][1], 0, 0, 0);
                acc[m][2] = __builtin_amdgcn_mfma_f32_16x16x32_bf16(a[m], b2f, acc[m][2], 0, 0, 0);
                acc[m][3] = __builtin_amdgcn_mfma_f32_16x16x32_bf16(a[m], b3f, acc[m][3], 0, 0, 0);
            }
        }
    }
    __builtin_amdgcn_s_barrier();   // all waves done reading Y
    // epi 2: bias+relu -> Y
#pragma unroll
    for (int m = 0; m < 4; ++m)
#pragma unroll
    for (int n = 0; n < 4; ++n) {
        int col = wid * 64 + n * 16 + arow;
#pragma unroll
        for (int r = 0; r < 4; ++r) {
            int row = m * 16 + (lane >> 4) * 4 + r;
            *(bhalf*)(Yb + yadr(row, 2 * col)) = f2b(fmaxf(acc[m][n][r] + bi2[n], 0.f));
        }
    }
    wlgkm0();
    __builtin_amdgcn_s_barrier();
    // ---------------- layer 3: MFMA, wave w owns rows w*16..w*16+15 ---------
    f32x4 z;
#pragma unroll
    for (int r = 0; r < 4; ++r) z[r] = 0.f;
    const int col3 = arow;
    for (int kc = 0; kc < 8; ++kc) {
        short8 a3 = *(const short8*)(Yb + yadr(wid * 16 + arow, kc * 64 + koff));
        short8 bw;
#pragma unroll
        for (int j = 0; j < 8; ++j) bw[j] = 0;
        if (col3 < DOUT) {
            int kbq = kc * 32 + (lane >> 4) * 8;
#pragma unroll
            for (int j = 0; j < 8; ++j)
                bw[j] = (short)f2b(W3[(kbq + j) * DOUT + col3]);
        }
        z = __builtin_amdgcn_mfma_f32_16x16x32_bf16(a3, bw, z, 0, 0, 0);
    }
    if (col3 < DOUT) {
        float bias = b3[col3];
#pragma unroll
        for (int rr = 0; rr < 4; ++rr) {
            int r = wid * 16 + (lane >> 4) * 4 + rr;
            int p2 = tstart + r;
            if ((p2 - gbase) < gcnt) {
                float v = z[rr] + bias;
                if (isB) {
                    int ro = perm[p2];
                    out[(size_t)ro * 3 + col3] = 1.f / (1.f + __expf(-v));
                } else {
                    out[(size_t)NB * 3 + p2] = v;
                }
            }
        }
    }
#undef ST_A
}

extern "C" void kernel_launch(void* const* d_in, const int* in_sizes, int n_in,
                              void* d_out, int out_size, void* d_ws, size_t ws_size,
                              hipStream_t stream) {
    (void)in_sizes; (void)n_in; (void)out_size; (void)ws_size;
    const float* emb   = (const float*)d_in[0];
    const float* speed = (const float*)d_in[1];
    const int*   cmd   = (const int*)d_in[2];
    const float* Wsi1  = (const float*)d_in[3];
    const float* bsi1  = (const float*)d_in[4];
    const float* Wsi2  = (const float*)d_in[5];
    const float* bsi2  = (const float*)d_in[6];
    const float* Wso1  = (const float*)d_in[7];
    const float* bso1  = (const float*)d_in[8];
    const float* Wso2  = (const float*)d_in[9];
    const float* bso2  = (const float*)d_in[10];
    const float* Wso3  = (const float*)d_in[11];
    const float* bso3  = (const float*)d_in[12];
    const float* Wb1   = (const float*)d_in[13];
    const float* bb1   = (const float*)d_in[14];
    const float* Wb2   = (const float*)d_in[15];
    const float* bb2   = (const float*)d_in[16];
    const float* Wb3   = (const float*)d_in[17];
    const float* bb3   = (const float*)d_in[18];
    float* out = (float*)d_out;

    char* ws = (char*)d_ws;
    bhalf* spb      = (bhalf*)(ws);
    int*   perm     = (int*)(ws + 16777216);
    int*   bcnt     = (int*)(ws + 17040896);
    int*   chunkoff = (int*)(ws + 17065472);
    int*   pad      = (int*)(ws + 17090048);
    bhalf* Wsi2T    = (bhalf*)(ws + 17090304);
    bhalf* Wso1T    = (bhalf*)(ws + 17155840);
    bhalf* Wso2T    = (bhalf*)(ws + 17483520);
    bhalf* Wb1T     = (bhalf*)(ws + 17614592);
    bhalf* Wb2T     = (bhalf*)(ws + 19580672);

    k_wprep<<<400, 256, 0, stream>>>(Wsi2, Wso1, Wso2, Wb1, Wb2,
                                     Wsi2T, Wso1T, Wso2T, Wb1T, Wb2T);
    k_prep<<<NB / 64, 256, 0, stream>>>(speed, Wsi1, bsi1, Wsi2T, bsi2, cmd,
                                        spb, bcnt);
    k_scan<<<1, 1024, 0, stream>>>(bcnt, chunkoff, pad);
    k_scatter<<<NB / 256, 256, 0, stream>>>(cmd, chunkoff, perm);
    k_head<<<NBRB + NB / 64, 256, 0, stream>>>(emb, spb,
                                               Wso1T, bso1, Wso2T, bso2, Wso3, bso3,
                                               Wb1T, bb1, Wb2T, bb2, Wb3, bb3,
                                               pad, perm, out);
}

// Round 8
// 178.910 us; speedup vs baseline: 1.0319x; 1.0319x over previous
//
#include <hip/hip_runtime.h>
#include <hip/hip_bf16.h>

// CILRS head, MI355X round 8.
// Pipe-sum analysis of r6: per CU-section, MFMA 19% + VALU(cvt) 25% +
// LDS-read 36% + LDS-write 12% ~= 92% busy across serialized per-wave pipes.
// Fix = fewer per-wave ops per MFMA:
//  - k1 (layer 1, BOTH heads): 64 rows x 512 cols, 4 waves x 128 cols.
//    Each wave: 8 A-reads + 32 cvt + 8 B-reads -> 32 MFMA (2x better ratio).
//    A staged once for both heads (block count halves). Y -> global bf16.
//  - k2 (layers 2+3, both heads): K=256, A = Y rows (linear, L3-hot).
//  - r6 fused k_head kept as fallback when ws_size < ~88MB.
// ws layout (bytes):
//   0        spb      : B*128 bf16 sp-latent (16,777,216)
//   16777216 perm     : (B+384) int32                 -> 17,040,896
//   17040896 bcnt     : [1024][6] int                 -> 17,065,472
//   17065472 chunkoff : [1024][6] int                 -> 17,090,048
//   17090048 pad      : pad[0..6]=offsets, pad[8+g]=totals
//   17090304 Wsi2T / 17155840 Wso1T / 17483520 Wso2T / 17614592 Wb1T /
//   19580672 Wb2T  (end 20,367,104)
//   20367104 Yg      : [66048][512] bf16 (67,633,152) end 88,000,256

#define NB 65536
#define NBRB 1030     // fallback branch-region blocks
#define NG2 1032      // k1/k2 grid (66048 padded rows / 64)
#define WS_NEED 88000256ULL

typedef __attribute__((ext_vector_type(8))) short short8;
typedef __attribute__((ext_vector_type(4))) float f32x4;
typedef unsigned short bhalf;
typedef unsigned int u32;

__device__ __forceinline__ bhalf f2b(float x) {
    __hip_bfloat16 h = __float2bfloat16(x);
    return *reinterpret_cast<bhalf*>(&h);
}
__device__ __forceinline__ void gll16(const void* g, void* l) {
    __builtin_amdgcn_global_load_lds(
        (const __attribute__((address_space(1))) u32*)g,
        (__attribute__((address_space(3))) u32*)l, 16, 0, 0);
}
// 64B-row bf16 tiles: phys = row*64 + (cb ^ (((row>>1)&3)<<4))
__device__ __forceinline__ int sadr(int row, int cb) {
    return row * 64 + (cb ^ (((row >> 1) & 3) << 4));
}
// 512B-row tile (fallback Y): phys = row*512 + (cb ^ ((row&7)<<4))
__device__ __forceinline__ int yadr(int row, int cb) {
    return row * 512 + (cb ^ ((row & 7) << 4));
}
// 1024B-row tile (k1/k2 overlay, 512 cols bf16)
__device__ __forceinline__ int yadr2(int row, int cb) {
    return row * 1024 + (cb ^ ((row & 7) << 4));
}
__device__ __forceinline__ void wvm10() { asm volatile("s_waitcnt vmcnt(10)" ::: "memory"); }
__device__ __forceinline__ void wvm6()  { asm volatile("s_waitcnt vmcnt(6)"  ::: "memory"); }
__device__ __forceinline__ void wvm0()  { asm volatile("s_waitcnt vmcnt(0)"  ::: "memory"); }
__device__ __forceinline__ void wlgkm0(){ asm volatile("s_waitcnt lgkmcnt(0)" ::: "memory"); }

// -------- weight transpose, 64x64 LDS tiles --------
__global__ __launch_bounds__(256) void k_wprep(
    const float* __restrict__ Wsi2, const float* __restrict__ Wso1,
    const float* __restrict__ Wso2, const float* __restrict__ Wb1,
    const float* __restrict__ Wb2,
    bhalf* __restrict__ Wsi2T, bhalf* __restrict__ Wso1T,
    bhalf* __restrict__ Wso2T, bhalf* __restrict__ Wb1T,
    bhalf* __restrict__ Wb2T) {
    __shared__ float T[64][65];
    const int id = blockIdx.x, t = threadIdx.x;
    const float* src; bhalf* dst; int K, N, tk, tn, b;
    if (id < 8)        { src = Wsi2; dst = Wsi2T; K = 256; N = 128; b = 0; int tl = id;      tk = tl / 2; tn = tl % 2; }
    else if (id < 48)  { src = Wso1; dst = Wso1T; K = 640; N = 256; b = 0; int tl = id - 8;  tk = tl / 4; tn = tl % 4; }
    else if (id < 64)  { src = Wso2; dst = Wso2T; K = 256; N = 256; b = 0; int tl = id - 48; tk = tl / 4; tn = tl % 4; }
    else if (id < 304) { src = Wb1;  dst = Wb1T;  K = 640; N = 256; int li = id - 64;  b = li / 40; int tl = li % 40; tk = tl / 4; tn = tl % 4; }
    else               { src = Wb2;  dst = Wb2T;  K = 256; N = 256; int li = id - 304; b = li / 16; int tl = li % 16; tk = tl / 4; tn = tl % 4; }
    const int k0 = tk * 64, n0 = tn * 64;
    src += (size_t)b * K * N; dst += (size_t)b * N * K;
    const int c = t & 63, r0 = t >> 6;
#pragma unroll
    for (int j = 0; j < 16; ++j) {
        int r = r0 + j * 4;
        T[r][c] = src[(size_t)(k0 + r) * N + n0 + c];
    }
    __syncthreads();
#pragma unroll
    for (int j = 0; j < 16; ++j) {
        int r = r0 + j * 4;
        dst[(size_t)(n0 + r) * K + k0 + c] = f2b(T[c][r]);
    }
}

// speed-latent + per-chunk command counts (NO atomics)
__global__ __launch_bounds__(256) void k_prep(
    const float* __restrict__ speed, const float* __restrict__ Wsi1,
    const float* __restrict__ bsi1, const bhalf* __restrict__ Wsi2T,
    const float* __restrict__ bsi2, const int* __restrict__ cmd,
    bhalf* __restrict__ spb, int* __restrict__ bcnt) {
    __shared__ bhalf A[64 * 72];
    __shared__ bhalf BT[128 * 72];
    const int t = threadIdx.x, lane = t & 63, wid = t >> 6;
    const int rbase = blockIdx.x * 64;
    if (wid == 0) {
        int c = cmd[rbase + lane] - 1;
        int v = 0;
#pragma unroll
        for (int g = 0; g < 6; ++g) {
            unsigned long long m = __ballot(c == g);
            if (lane == g) v = (int)__popcll(m);
        }
        if (lane < 6) bcnt[blockIdx.x * 6 + lane] = v;
    }
    const int wm = wid >> 1, wn = wid & 1;
    f32x4 acc[2][4];
    for (int m = 0; m < 2; ++m) for (int n = 0; n < 4; ++n)
        for (int r = 0; r < 4; ++r) acc[m][n][r] = 0.f;
    const int ar = t >> 2, kp = (t & 3) * 16;
    const float s = speed[rbase + ar];
    for (int kc = 0; kc < 4; ++kc) {
        short8 w0, w1;
#pragma unroll
        for (int j = 0; j < 8; ++j) {
            int k = kc * 64 + kp + j;
            w0[j] = (short)f2b(fmaxf(fmaf(s, Wsi1[k], bsi1[k]), 0.f));
            w1[j] = (short)f2b(fmaxf(fmaf(s, Wsi1[k + 8], bsi1[k + 8]), 0.f));
        }
        *(short8*)&A[ar * 72 + kp] = w0;
        *(short8*)&A[ar * 72 + kp + 8] = w1;
#pragma unroll
        for (int j = 0; j < 4; ++j) {
            int ch = t + j * 256;
            int n2 = ch >> 3, ko = (ch & 7) * 8;
            *(short8*)&BT[n2 * 72 + ko] =
                *(const short8*)(Wsi2T + n2 * 256 + kc * 64 + ko);
        }
        __syncthreads();
#pragma unroll
        for (int ks = 0; ks < 2; ++ks) {
            short8 a[2], b[4];
#pragma unroll
            for (int m = 0; m < 2; ++m)
                a[m] = *(const short8*)&A[(wm * 32 + m * 16 + (lane & 15)) * 72 + ks * 32 + (lane >> 4) * 8];
#pragma unroll
            for (int n = 0; n < 4; ++n)
                b[n] = *(const short8*)&BT[(wn * 64 + n * 16 + (lane & 15)) * 72 + ks * 32 + (lane >> 4) * 8];
#pragma unroll
            for (int m = 0; m < 2; ++m)
#pragma unroll
                for (int n = 0; n < 4; ++n)
                    acc[m][n] = __builtin_amdgcn_mfma_f32_16x16x32_bf16(a[m], b[n], acc[m][n], 0, 0, 0);
        }
        __syncthreads();
    }
#pragma unroll
    for (int m = 0; m < 2; ++m)
#pragma unroll
    for (int n = 0; n < 4; ++n) {
        int col = wn * 64 + n * 16 + (lane & 15);
        float bias = bsi2[col];
#pragma unroll
        for (int r = 0; r < 4; ++r) {
            int row = rbase + wm * 32 + m * 16 + (lane >> 4) * 4 + r;
            spb[row * 128 + col] = f2b(acc[m][n][r] + bias);
        }
    }
}

__global__ __launch_bounds__(1024) void k_scan(
    const int* __restrict__ bcnt, int* __restrict__ chunkoff,
    int* __restrict__ pad) {
    __shared__ int sc[1024];
    __shared__ int tot[8];
    __shared__ int spo[8];
    const int t = threadIdx.x;
    for (int g = 0; g < 6; ++g) {
        int v = bcnt[t * 6 + g];
        sc[t] = v;
        __syncthreads();
        for (int s = 1; s < 1024; s <<= 1) {
            int u = (t >= s) ? sc[t - s] : 0;
            __syncthreads();
            sc[t] += u;
            __syncthreads();
        }
        if (t == 1023) tot[g] = sc[t];
        chunkoff[t * 6 + g] = sc[t] - v;
        __syncthreads();
    }
    if (t == 0) {
        int off = 0;
        for (int g = 0; g < 6; ++g) {
            spo[g] = off; pad[g] = off; pad[8 + g] = tot[g];
            off += ((tot[g] + 63) >> 6) << 6;
        }
        spo[6] = off; pad[6] = off;
    }
    __syncthreads();
    for (int g = 0; g < 6; ++g) chunkoff[t * 6 + g] += spo[g];
}

__global__ __launch_bounds__(256) void k_scatter(
    const int* __restrict__ cmd, const int* __restrict__ chunkoff,
    int* __restrict__ perm) {
    const int lane = threadIdx.x & 63, w = threadIdx.x >> 6;
    const int chunk = blockIdx.x * 4 + w;
    const int idx = chunk * 64 + lane;
    const int c = cmd[idx] - 1;
#pragma unroll
    for (int g = 0; g < 6; ++g) {
        unsigned long long m = __ballot(c == g);
        if (c == g) {
            int pos = chunkoff[chunk * 6 + g] + (int)__popcll(m & ((1ull << lane) - 1ull));
            perm[pos] = idx;
        }
    }
}

// ===================== k1: layer 1, both heads, Y -> global ==================
__global__ __launch_bounds__(256, 2) void k1(
    const float* __restrict__ emb, const bhalf* __restrict__ spb,
    const bhalf* __restrict__ Wso1T, const float* __restrict__ bso1,
    const bhalf* __restrict__ Wb1T, const float* __restrict__ bb1,
    const int* __restrict__ pad, const int* __restrict__ perm,
    bhalf* __restrict__ Yg) {
    __shared__ __align__(16) char L[81920];
    char* const SA0 = L;            // 2 x 8192
    char* const SB0 = L + 16384;    // 2 x 32768 (branch 16K + speed 16K each)
    const int t = threadIdx.x, lane = t & 63, wid = t >> 6;
    const int tstart = blockIdx.x * 64;
    if (tstart >= pad[6]) return;
    int g = 0;
    while (pad[g + 1] <= tstart) ++g;
    const int gbase = pad[g], gcnt = pad[8 + g];
    const bhalf* W1b = Wb1T + (size_t)g * (256 * 640);

    const int rowA0 = t >> 3, rowA1 = rowA0 + 32, rowS = t >> 2;
    int p0 = tstart + rowA0, p1 = tstart + rowA1, pS = tstart + rowS;
    const int ra0 = ((p0 - gbase) < gcnt) ? perm[p0] : 0;
    const int ra1 = ((p1 - gbase) < gcnt) ? perm[p1] : 0;
    const int raS = ((pS - gbase) < gcnt) ? perm[pS] : 0;
    const int lcA0 = ((t & 7) * 16) ^ ((rowA0 & 7) << 4);
    const int lcA1 = ((t & 7) * 16) ^ ((rowA1 & 7) << 4);
    const int lcS  = ((t & 3) * 16) ^ (((rowS >> 1) & 3) << 4);
    const char* embp0 = (const char*)(emb + (size_t)ra0 * 512);
    const char* embp1 = (const char*)(emb + (size_t)ra1 * 512);
    const char* spbp  = (const char*)(spb + (size_t)raS * 128);
    const int dstA = t * 16;
    const int rB = t >> 2, cB = (t & 3) * 16;

#define ST_A(KN, BUF) do { int kn_ = (KN); char* d_ = SA0 + (BUF) * 8192 + dstA; \
        if (kn_ < 16) {                                                           \
            gll16(embp0 + kn_ * 128 + lcA0, d_);                                  \
            gll16(embp1 + kn_ * 128 + lcA1, d_ + 4096);                           \
        } else {                                                                  \
            gll16(spbp + (kn_ - 16) * 64 + lcS, d_);                              \
            gll16(spbp + (kn_ - 16) * 64 + lcS, d_ + 4096);                       \
        } } while (0)
#define ST_B(KN, BUF) do {                                                        \
        _Pragma("unroll")                                                         \
        for (int j_ = 0; j_ < 4; ++j_) {                                          \
            int row_ = rB + j_ * 64;                                              \
            int p_ = row_ * 64 + cB;                                              \
            int lc_ = cB ^ (((row_ >> 1) & 3) << 4);                              \
            gll16((const char*)W1b + (size_t)row_ * 1280 + (KN) * 64 + lc_,       \
                  SB0 + (BUF) * 32768 + p_);                                      \
            gll16((const char*)Wso1T + (size_t)row_ * 1280 + (KN) * 64 + lc_,     \
                  SB0 + (BUF) * 32768 + 16384 + p_);                              \
        } } while (0)

    const int arow = lane & 15, koff = (lane >> 4) * 16;
    float bi1[8];
#pragma unroll
    for (int n = 0; n < 4; ++n) {
        bi1[n]     = bb1[g * 256 + wid * 64 + n * 16 + arow];
        bi1[n + 4] = bso1[wid * 64 + n * 16 + arow];
    }

    f32x4 acc[4][8];
#pragma unroll
    for (int m = 0; m < 4; ++m)
#pragma unroll
        for (int n = 0; n < 8; ++n)
#pragma unroll
            for (int r = 0; r < 4; ++r) acc[m][n][r] = 0.f;

    ST_A(0, 0); ST_B(0, 0);                  // 10 outstanding
    for (int kc = 0; kc < 20; ++kc) {
        const int buf = kc & 1;
        if (kc < 19) { ST_A(kc + 1, buf ^ 1); ST_B(kc + 1, buf ^ 1); wvm10(); }
        else         { wvm0(); }
        __builtin_amdgcn_s_barrier();
        const char* SAc = SA0 + buf * 8192;
        const char* SBc = SB0 + buf * 32768;
        short8 a[4], b[8];
#pragma unroll
        for (int n = 0; n < 4; ++n) {
            b[n]     = *(const short8*)(SBc + sadr(wid * 64 + n * 16 + arow, koff));
            b[n + 4] = *(const short8*)(SBc + 16384 + sadr(wid * 64 + n * 16 + arow, koff));
        }
        if (kc < 16) {
#pragma unroll
            for (int m = 0; m < 4; ++m) {
                int row = m * 16 + arow;
                int sw = (row & 7) << 4;
                int c0 = (lane >> 4) * 32;
                float4 f0 = *(const float4*)(SAc + row * 128 + (c0 ^ sw));
                float4 f1 = *(const float4*)(SAc + row * 128 + ((c0 + 16) ^ sw));
                a[m][0] = (short)f2b(f0.x); a[m][1] = (short)f2b(f0.y);
                a[m][2] = (short)f2b(f0.z); a[m][3] = (short)f2b(f0.w);
                a[m][4] = (short)f2b(f1.x); a[m][5] = (short)f2b(f1.y);
                a[m][6] = (short)f2b(f1.z); a[m][7] = (short)f2b(f1.w);
            }
        } else {
#pragma unroll
            for (int m = 0; m < 4; ++m)
                a[m] = *(const short8*)(SAc + sadr(m * 16 + arow, koff));
        }
#pragma unroll
        for (int m = 0; m < 4; ++m)
#pragma unroll
            for (int n = 0; n < 8; ++n)
                acc[m][n] = __builtin_amdgcn_mfma_f32_16x16x32_bf16(a[m], b[n], acc[m][n], 0, 0, 0);
        __builtin_amdgcn_s_barrier();
    }
    // epilogue: bias+relu -> LDS overlay [0,65536), then coalesced copy-out
#pragma unroll
    for (int m = 0; m < 4; ++m)
#pragma unroll
    for (int n = 0; n < 8; ++n) {
        int col = (n < 4) ? (wid * 64 + n * 16 + arow)
                          : (256 + wid * 64 + (n - 4) * 16 + arow);
#pragma unroll
        for (int r = 0; r < 4; ++r) {
            int row = m * 16 + (lane >> 4) * 4 + r;
            *(bhalf*)(L + yadr2(row, 2 * col)) = f2b(fmaxf(acc[m][n][r] + bi1[n], 0.f));
        }
    }
    wlgkm0();
    __builtin_amdgcn_s_barrier();
    char* Ygb = (char*)Yg + (size_t)tstart * 1024;
#pragma unroll
    for (int j = 0; j < 16; ++j) {
        int p = t * 16 + j * 4096;
        int row = p >> 10, cb = p & 1023;
        uint4 v = *(const uint4*)(L + row * 1024 + (cb ^ ((row & 7) << 4)));
        *(uint4*)(Ygb + (size_t)row * 1024 + cb) = v;
    }
#undef ST_A
#undef ST_B
}

// ===================== k2: layers 2+3, both heads ============================
__global__ __launch_bounds__(256, 2) void k2(
    const bhalf* __restrict__ Yg,
    const bhalf* __restrict__ Wso2T, const float* __restrict__ bso2,
    const float* __restrict__ Wso3, const float* __restrict__ bso3,
    const bhalf* __restrict__ Wb2T, const float* __restrict__ bb2,
    const float* __restrict__ Wb3, const float* __restrict__ bb3,
    const int* __restrict__ pad, const int* __restrict__ perm,
    float* __restrict__ out) {
    __shared__ __align__(16) char L[81920];
    char* const SA0 = L;            // 2 x 8192 (branch 4K + speed 4K each)
    char* const SB0 = L + 16384;    // 2 x 32768
    const int t = threadIdx.x, lane = t & 63, wid = t >> 6;
    const int tstart = blockIdx.x * 64;
    if (tstart >= pad[6]) return;
    int g = 0;
    while (pad[g + 1] <= tstart) ++g;
    const int gbase = pad[g], gcnt = pad[8 + g];
    const bhalf* W2b = Wb2T + (size_t)g * (256 * 256);
    const float* W3b = Wb3 + (size_t)g * (256 * 3);
    const float* b3b = bb3 + g * 3;

    const int rowY = t >> 2, cA = (t & 3) * 16;
    const int lcA = cA ^ (((rowY >> 1) & 3) << 4);
    const char* ygp = (const char*)Yg + (size_t)(tstart + rowY) * 1024;
    const int dstA = t * 16;
    const int rB = t >> 2, cB = (t & 3) * 16;

#define ST_A2(KC, BUF) do { char* d_ = SA0 + (BUF) * 8192 + dstA;                \
        gll16(ygp + (KC) * 64 + lcA, d_);                                         \
        gll16(ygp + 512 + (KC) * 64 + lcA, d_ + 4096);                            \
    } while (0)
#define ST_B2(KC, BUF) do {                                                       \
        _Pragma("unroll")                                                         \
        for (int j_ = 0; j_ < 4; ++j_) {                                          \
            int row_ = rB + j_ * 64;                                              \
            int p_ = row_ * 64 + cB;                                              \
            int lc_ = cB ^ (((row_ >> 1) & 3) << 4);                              \
            gll16((const char*)W2b + (size_t)row_ * 512 + (KC) * 64 + lc_,        \
                  SB0 + (BUF) * 32768 + p_);                                      \
            gll16((const char*)Wso2T + (size_t)row_ * 512 + (KC) * 64 + lc_,      \
                  SB0 + (BUF) * 32768 + 16384 + p_);                              \
        } } while (0)

    const int arow = lane & 15, koff = (lane >> 4) * 16;
    float bi2[8];
#pragma unroll
    for (int n = 0; n < 4; ++n) {
        bi2[n]     = bb2[g * 256 + wid * 64 + n * 16 + arow];
        bi2[n + 4] = bso2[wid * 64 + n * 16 + arow];
    }

    f32x4 acc[4][8];
#pragma unroll
    for (int m = 0; m < 4; ++m)
#pragma unroll
        for (int n = 0; n < 8; ++n)
#pragma unroll
            for (int r = 0; r < 4; ++r) acc[m][n][r] = 0.f;

    ST_A2(0, 0); ST_B2(0, 0);
    for (int kc = 0; kc < 8; ++kc) {
        const int buf = kc & 1;
        if (kc < 7) { ST_A2(kc + 1, buf ^ 1); ST_B2(kc + 1, buf ^ 1); wvm10(); }
        else        { wvm0(); }
        __builtin_amdgcn_s_barrier();
        const char* SAc = SA0 + buf * 8192;
        const char* SBc = SB0 + buf * 32768;
        short8 aB[4], aS[4], b[8];
#pragma unroll
        for (int m = 0; m < 4; ++m) {
            aB[m] = *(const short8*)(SAc + sadr(m * 16 + arow, koff));
            aS[m] = *(const short8*)(SAc + 4096 + sadr(m * 16 + arow, koff));
        }
#pragma unroll
        for (int n = 0; n < 4; ++n) {
            b[n]     = *(const short8*)(SBc + sadr(wid * 64 + n * 16 + arow, koff));
            b[n + 4] = *(const short8*)(SBc + 16384 + sadr(wid * 64 + n * 16 + arow, koff));
        }
#pragma unroll
        for (int m = 0; m < 4; ++m)
#pragma unroll
            for (int n = 0; n < 4; ++n) {
                acc[m][n]     = __builtin_amdgcn_mfma_f32_16x16x32_bf16(aB[m], b[n],     acc[m][n],     0, 0, 0);
                acc[m][n + 4] = __builtin_amdgcn_mfma_f32_16x16x32_bf16(aS[m], b[n + 4], acc[m][n + 4], 0, 0, 0);
            }
        __builtin_amdgcn_s_barrier();
    }
    // epi: bias+relu -> h2 LDS overlay [0,65536)
#pragma unroll
    for (int m = 0; m < 4; ++m)
#pragma unroll
    for (int n = 0; n < 8; ++n) {
        int col = (n < 4) ? (wid * 64 + n * 16 + arow)
                          : (256 + wid * 64 + (n - 4) * 16 + arow);
#pragma unroll
        for (int r = 0; r < 4; ++r) {
            int row = m * 16 + (lane >> 4) * 4 + r;
            *(bhalf*)(L + yadr2(row, 2 * col)) = f2b(fmaxf(acc[m][n][r] + bi2[n], 0.f));
        }
    }
    wlgkm0();
    __builtin_amdgcn_s_barrier();
    // layer 3: wave w owns rows w*16..w*16+15; branch (3 cols) + speed (1 col)
    f32x4 zB, zS;
#pragma unroll
    for (int r = 0; r < 4; ++r) { zB[r] = 0.f; zS[r] = 0.f; }
    const int col3 = arow;
    for (int kc = 0; kc < 8; ++kc) {
        short8 a3b = *(const short8*)(L + yadr2(wid * 16 + arow, kc * 64 + koff));
        short8 a3s = *(const short8*)(L + yadr2(wid * 16 + arow, 512 + kc * 64 + koff));
        short8 bwB, bwS;
#pragma unroll
        for (int j = 0; j < 8; ++j) { bwB[j] = 0; bwS[j] = 0; }
        int kb = kc * 32 + (lane >> 4) * 8;
        if (col3 < 3) {
#pragma unroll
            for (int j = 0; j < 8; ++j)
                bwB[j] = (short)f2b(W3b[(kb + j) * 3 + col3]);
        }
        if (col3 < 1) {
#pragma unroll
            for (int j = 0; j < 8; ++j)
                bwS[j] = (short)f2b(Wso3[kb + j]);
        }
        zB = __builtin_amdgcn_mfma_f32_16x16x32_bf16(a3b, bwB, zB, 0, 0, 0);
        zS = __builtin_amdgcn_mfma_f32_16x16x32_bf16(a3s, bwS, zS, 0, 0, 0);
    }
#pragma unroll
    for (int rr = 0; rr < 4; ++rr) {
        int r = wid * 16 + (lane >> 4) * 4 + rr;
        int p2 = tstart + r;
        if ((p2 - gbase) < gcnt) {
            int ro = perm[p2];
            if (col3 < 3) {
                float v = zB[rr] + b3b[col3];
                out[(size_t)ro * 3 + col3] = 1.f / (1.f + __expf(-v));
            }
            if (col3 < 1) {
                out[(size_t)NB * 3 + ro] = zS[rr] + bso3[0];
            }
        }
    }
#undef ST_A2
#undef ST_B2
}

// ============ fallback fused head (round-6, used if ws too small) ===========
__global__ __launch_bounds__(256, 3) void k_head(
    const float* __restrict__ emb, const bhalf* __restrict__ spb,
    const bhalf* __restrict__ Wso1T, const float* __restrict__ bso1,
    const bhalf* __restrict__ Wso2T, const float* __restrict__ bso2,
    const float* __restrict__ Wso3, const float* __restrict__ bso3,
    const bhalf* __restrict__ Wb1T, const float* __restrict__ bb1,
    const bhalf* __restrict__ Wb2T, const float* __restrict__ bb2,
    const float* __restrict__ Wb3, const float* __restrict__ bb3,
    const int* __restrict__ pad, const int* __restrict__ perm,
    float* __restrict__ out) {
    __shared__ __align__(16) char L[49152];
    char* const SB0 = L;
    char* const SAr = L + 32768;
    char* const Yb  = L;
    const int t = threadIdx.x, lane = t & 63, wid = t >> 6;
    const bool isB = blockIdx.x < NBRB;
    int tstart, DOUT, gcnt, gbase;
    const bhalf *W1T, *W2T; const float *b1, *b2, *W3, *b3;
    if (isB) {
        tstart = blockIdx.x * 64;
        if (tstart >= pad[6]) return;
        int g = 0;
        while (pad[g + 1] <= tstart) ++g;
        gbase = pad[g]; gcnt = pad[8 + g];
        W1T = Wb1T + (size_t)g * (256 * 640); b1 = bb1 + g * 256;
        W2T = Wb2T + (size_t)g * (256 * 256); b2 = bb2 + g * 256;
        W3  = Wb3  + (size_t)g * (256 * 3);   b3 = bb3 + g * 3;
        DOUT = 3;
    } else {
        tstart = (blockIdx.x - NBRB) * 64;
        gbase = 0; gcnt = NB;
        W1T = Wso1T; b1 = bso1; W2T = Wso2T; b2 = bso2; W3 = Wso3; b3 = bso3;
        DOUT = 1;
    }
    const int rowA0 = t >> 3, rowA1 = rowA0 + 32, rowS = t >> 2;
    int ra0, ra1, raS;
    if (isB) {
        int p0 = tstart + rowA0, p1 = tstart + rowA1, pS = tstart + rowS;
        ra0 = ((p0 - gbase) < gcnt) ? perm[p0] : 0;
        ra1 = ((p1 - gbase) < gcnt) ? perm[p1] : 0;
        raS = ((pS - gbase) < gcnt) ? perm[pS] : 0;
    } else {
        ra0 = tstart + rowA0; ra1 = tstart + rowA1; raS = tstart + rowS;
    }
    const int lcA0 = ((t & 7) * 16) ^ ((rowA0 & 7) << 4);
    const int lcA1 = ((t & 7) * 16) ^ ((rowA1 & 7) << 4);
    const int lcS  = ((t & 3) * 16) ^ (((rowS >> 1) & 3) << 4);
    const char* embp0 = (const char*)(emb + (size_t)ra0 * 512);
    const char* embp1 = (const char*)(emb + (size_t)ra1 * 512);
    const char* spbp  = (const char*)(spb + (size_t)raS * 128);
    const int dstA = t * 16;
    const int rB = t >> 2, cB = (t & 3) * 16;
#define ST_A(KN, BUF) do { int kn_ = (KN); char* d_ = SAr + (BUF) * 8192 + dstA; \
        if (kn_ < 16) {                                                           \
            gll16(embp0 + kn_ * 128 + lcA0, d_);                                  \
            gll16(embp1 + kn_ * 128 + lcA1, d_ + 4096);                           \
        } else {                                                                  \
            gll16(spbp + (kn_ - 16) * 64 + lcS, d_);                              \
            gll16(spbp + (kn_ - 16) * 64 + lcS, d_ + 4096);                       \
        } } while (0)
#define ST_B1(KN, BUF) do {                                                       \
        _Pragma("unroll")                                                         \
        for (int j_ = 0; j_ < 4; ++j_) {                                          \
            int row_ = rB + j_ * 64;                                              \
            int p_ = row_ * 64 + cB;                                              \
            int lc_ = cB ^ (((row_ >> 1) & 3) << 4);                              \
            gll16((const char*)W1T + (size_t)row_ * 1280 + (KN) * 64 + lc_,       \
                  SB0 + (BUF) * 16384 + p_);                                      \
        } } while (0)
#define ST_B2(KB) do {                                                            \
        _Pragma("unroll")                                                         \
        for (int j_ = 0; j_ < 4; ++j_) {                                          \
            int row_ = rB + j_ * 64;                                              \
            int p_ = row_ * 64 + cB;                                              \
            int lc_ = cB ^ (((row_ >> 1) & 3) << 4);                              \
            gll16((const char*)W2T + (size_t)row_ * 512 + (KB) + lc_,             \
                  SAr + p_);                                                      \
        } } while (0)
    const int arow = lane & 15, koff = (lane >> 4) * 16;
    float bi1[4], bi2[4];
#pragma unroll
    for (int n = 0; n < 4; ++n) {
        bi1[n] = b1[wid * 64 + n * 16 + arow];
        bi2[n] = b2[wid * 64 + n * 16 + arow];
    }
    f32x4 acc[4][4];
#pragma unroll
    for (int m = 0; m < 4; ++m)
#pragma unroll
        for (int n = 0; n < 4; ++n)
#pragma unroll
            for (int r = 0; r < 4; ++r) acc[m][n][r] = 0.f;
    ST_A(0, 0); ST_B1(0, 0);
    for (int kc = 0; kc < 20; ++kc) {
        const int buf = kc & 1;
        if (kc < 19) { ST_A(kc + 1, buf ^ 1); ST_B1(kc + 1, buf ^ 1); wvm6(); }
        else         { wvm0(); }
        __builtin_amdgcn_s_barrier();
        const char* SAc = SAr + buf * 8192;
        const char* SBc = SB0 + buf * 16384;
        short8 a[4], b[4];
#pragma unroll
        for (int n = 0; n < 4; ++n)
            b[n] = *(const short8*)(SBc + sadr(wid * 64 + n * 16 + arow, koff));
        if (kc < 16) {
#pragma unroll
            for (int m = 0; m < 4; ++m) {
                int row = m * 16 + arow;
                int sw = (row & 7) << 4;
                int c0 = (lane >> 4) * 32;
                float4 f0 = *(const float4*)(SAc + row * 128 + (c0 ^ sw));
                float4 f1 = *(const float4*)(SAc + row * 128 + ((c0 + 16) ^ sw));
                a[m][0] = (short)f2b(f0.x); a[m][1] = (short)f2b(f0.y);
                a[m][2] = (short)f2b(f0.z); a[m][3] = (short)f2b(f0.w);
                a[m][4] = (short)f2b(f1.x); a[m][5] = (short)f2b(f1.y);
                a[m][6] = (short)f2b(f1.z); a[m][7] = (short)f2b(f1.w);
            }
        } else {
#pragma unroll
            for (int m = 0; m < 4; ++m)
                a[m] = *(const short8*)(SAc + sadr(m * 16 + arow, koff));
        }
#pragma unroll
        for (int m = 0; m < 4; ++m)
#pragma unroll
            for (int n = 0; n < 4; ++n)
                acc[m][n] = __builtin_amdgcn_mfma_f32_16x16x32_bf16(a[m], b[n], acc[m][n], 0, 0, 0);
        __builtin_amdgcn_s_barrier();
    }
#pragma unroll
    for (int m = 0; m < 4; ++m)
#pragma unroll
    for (int n = 0; n < 4; ++n) {
        int col = wid * 64 + n * 16 + arow;
#pragma unroll
        for (int r = 0; r < 4; ++r) {
            int row = m * 16 + (lane >> 4) * 4 + r;
            *(bhalf*)(Yb + yadr(row, 2 * col)) = f2b(fmaxf(acc[m][n][r] + bi1[n], 0.f));
            acc[m][n][r] = 0.f;
        }
    }
    ST_B2(0);
    wlgkm0();
    wvm0();
    __builtin_amdgcn_s_barrier();
    for (int kc = 0; kc < 8; ++kc) {
        short8 a[4], b[4];
#pragma unroll
        for (int m = 0; m < 4; ++m)
            a[m] = *(const short8*)(Yb + yadr(m * 16 + arow, kc * 64 + koff));
#pragma unroll
        for (int n = 0; n < 4; ++n)
            b[n] = *(const short8*)(SAr + sadr(wid * 64 + n * 16 + arow, koff));
#pragma unroll
        for (int m = 0; m < 4; ++m)
#pragma unroll
            for (int n = 0; n < 4; ++n)
                acc[m][n] = __builtin_amdgcn_mfma_f32_16x16x32_bf16(a[m], b[n], acc[m][n], 0, 0, 0);
        __builtin_amdgcn_s_barrier();
        if (kc < 7) { ST_B2((kc + 1) * 64); wvm0(); }
        __builtin_amdgcn_s_barrier();
    }
#pragma unroll
    for (int m = 0; m < 4; ++m)
#pragma unroll
    for (int n = 0; n < 4; ++n) {
        int col = wid * 64 + n * 16 + arow;
#pragma unroll
        for (int r = 0; r < 4; ++r) {
            int row = m * 16 + (lane >> 4) * 4 + r;
            *(bhalf*)(Yb + yadr(row, 2 * col)) = f2b(fmaxf(acc[m][n][r] + bi2[n], 0.f));
        }
    }
    wlgkm0();
    __builtin_amdgcn_s_barrier();
    f32x4 z;
#pragma unroll
    for (int r = 0; r < 4; ++r) z[r] = 0.f;
    const int col3 = arow;
    for (int kc = 0; kc < 8; ++kc) {
        short8 a3 = *(const short8*)(Yb + yadr(wid * 16 + arow, kc * 64 + koff));
        short8 bw;
#pragma unroll
        for (int j = 0; j < 8; ++j) bw[j] = 0;
        if (col3 < DOUT) {
            int kbq = kc * 32 + (lane >> 4) * 8;
#pragma unroll
            for (int j = 0; j < 8; ++j)
                bw[j] = (short)f2b(W3[(kbq + j) * DOUT + col3]);
        }
        z = __builtin_amdgcn_mfma_f32_16x16x32_bf16(a3, bw, z, 0, 0, 0);
    }
    if (col3 < DOUT) {
        float bias = b3[col3];
#pragma unroll
        for (int rr = 0; rr < 4; ++rr) {
            int r = wid * 16 + (lane >> 4) * 4 + rr;
            int p2 = tstart + r;
            if ((p2 - gbase) < gcnt) {
                float v = z[rr] + bias;
                if (isB) {
                    int ro = perm[p2];
                    out[(size_t)ro * 3 + col3] = 1.f / (1.f + __expf(-v));
                } else {
                    out[(size_t)NB * 3 + p2] = v;
                }
            }
        }
    }
#undef ST_A
#undef ST_B1
#undef ST_B2
}

extern "C" void kernel_launch(void* const* d_in, const int* in_sizes, int n_in,
                              void* d_out, int out_size, void* d_ws, size_t ws_size,
                              hipStream_t stream) {
    (void)in_sizes; (void)n_in; (void)out_size;
    const float* emb   = (const float*)d_in[0];
    const float* speed = (const float*)d_in[1];
    const int*   cmd   = (const int*)d_in[2];
    const float* Wsi1  = (const float*)d_in[3];
    const float* bsi1  = (const float*)d_in[4];
    const float* Wsi2  = (const float*)d_in[5];
    const float* bsi2  = (const float*)d_in[6];
    const float* Wso1  = (const float*)d_in[7];
    const float* bso1  = (const float*)d_in[8];
    const float* Wso2  = (const float*)d_in[9];
    const float* bso2  = (const float*)d_in[10];
    const float* Wso3  = (const float*)d_in[11];
    const float* bso3  = (const float*)d_in[12];
    const float* Wb1   = (const float*)d_in[13];
    const float* bb1   = (const float*)d_in[14];
    const float* Wb2   = (const float*)d_in[15];
    const float* bb2   = (const float*)d_in[16];
    const float* Wb3   = (const float*)d_in[17];
    const float* bb3   = (const float*)d_in[18];
    float* out = (float*)d_out;

    char* ws = (char*)d_ws;
    bhalf* spb      = (bhalf*)(ws);
    int*   perm     = (int*)(ws + 16777216);
    int*   bcnt     = (int*)(ws + 17040896);
    int*   chunkoff = (int*)(ws + 17065472);
    int*   pad      = (int*)(ws + 17090048);
    bhalf* Wsi2T    = (bhalf*)(ws + 17090304);
    bhalf* Wso1T    = (bhalf*)(ws + 17155840);
    bhalf* Wso2T    = (bhalf*)(ws + 17483520);
    bhalf* Wb1T     = (bhalf*)(ws + 17614592);
    bhalf* Wb2T     = (bhalf*)(ws + 19580672);
    bhalf* Yg       = (bhalf*)(ws + 20367104);

    k_wprep<<<400, 256, 0, stream>>>(Wsi2, Wso1, Wso2, Wb1, Wb2,
                                     Wsi2T, Wso1T, Wso2T, Wb1T, Wb2T);
    k_prep<<<NB / 64, 256, 0, stream>>>(speed, Wsi1, bsi1, Wsi2T, bsi2, cmd,
                                        spb, bcnt);
    k_scan<<<1, 1024, 0, stream>>>(bcnt, chunkoff, pad);
    k_scatter<<<NB / 256, 256, 0, stream>>>(cmd, chunkoff, perm);
    if (ws_size >= WS_NEED) {
        k1<<<NG2, 256, 0, stream>>>(emb, spb, Wso1T, bso1, Wb1T, bb1,
                                    pad, perm, Yg);
        k2<<<NG2, 256, 0, stream>>>(Yg, Wso2T, bso2, Wso3, bso3,
                                    Wb2T, bb2, Wb3, bb3, pad, perm, out);
    } else {
        k_head<<<NBRB + NB / 64, 256, 0, stream>>>(emb, spb,
                                                   Wso1T, bso1, Wso2T, bso2, Wso3, bso3,
                                                   Wb1T, bb1, Wb2T, bb2, Wb3, bb3,
                                                   pad, perm, out);
    }
}